// Round 1
// baseline (177.509 us; speedup 1.0000x reference)
//
#include <hip/hip_runtime.h>

// out = mean_i( rank_of_diag(cos_sim(x1,x2))_i < nper ), nper = S/100+1.
// rank_i = #{ j != i : dot(x1_i,x2_j)*inv||x2_j|| > dot(x1_i,x2_i)*inv||x2_i|| }
// GEMM via fp16x3 (Markidis split) MFMA: x=hi+lo; hi*hi + hi*lo + lo*hi.
// Dropped lo*lo ~2^-22 rel/term -> dot err ~3e-6 << 4.5e-3 order-stat spacing.
//
// This version: hi/lo split precomputed ONCE in prep (was re-converted 64x per
// row in count); staging via global_load_lds dwordx4 DMA into fragment-ordered
// LDS (no VGPR roundtrip, no ds_write bank conflicts); double-buffered BK=32
// with early-issued loads so the barrier vmcnt-drain lands after the MFMAs.

#define KDIM 128

typedef _Float16 half8 __attribute__((ext_vector_type(8)));
typedef float floatx16 __attribute__((ext_vector_type(16)));

static __device__ __forceinline__ void gload16(const void* g, void* l)
{
    __builtin_amdgcn_global_load_lds(
        (__attribute__((address_space(1))) void*)(g),
        (__attribute__((address_space(3))) void*)(l),
        16, 0, 0);
}

// ---------- Kernel A: 1/||x2||, diag threshold, zero counters, fp16 hi/lo planes ----------
__global__ __launch_bounds__(256) void prep_kernel(
    const float* __restrict__ x1, const float* __restrict__ x2,
    float* __restrict__ invn, float* __restrict__ thr,
    int* __restrict__ row_count,
    unsigned* __restrict__ x1h, unsigned* __restrict__ x1l,
    unsigned* __restrict__ x2h, unsigned* __restrict__ x2l,
    int B, int S, int wplanes)
{
    const int wave = threadIdx.x >> 6;
    const int lane = threadIdx.x & 63;
    const int row = blockIdx.x * 4 + wave;
    if (row >= S && row >= B) return;

    float s22 = 0.f, s12 = 0.f;
    float2 a = make_float2(0.f, 0.f), b = make_float2(0.f, 0.f);
    if (row < B) a = ((const float2*)&x1[(size_t)row * KDIM])[lane];
    if (row < S) {
        b = ((const float2*)&x2[(size_t)row * KDIM])[lane];
        s22 = fmaf(b.x, b.x, b.y * b.y);
        s12 = fmaf(a.x, b.x, a.y * b.y);
    }

    if (wplanes) {
        if (row < B) {
            union { _Float16 h[2]; unsigned u; } hh, ll;
            hh.h[0] = (_Float16)a.x; ll.h[0] = (_Float16)(a.x - (float)hh.h[0]);
            hh.h[1] = (_Float16)a.y; ll.h[1] = (_Float16)(a.y - (float)hh.h[1]);
            x1h[(size_t)row * 64 + lane] = hh.u;
            x1l[(size_t)row * 64 + lane] = ll.u;
        }
        if (row < S) {
            union { _Float16 h[2]; unsigned u; } hh, ll;
            hh.h[0] = (_Float16)b.x; ll.h[0] = (_Float16)(b.x - (float)hh.h[0]);
            hh.h[1] = (_Float16)b.y; ll.h[1] = (_Float16)(b.y - (float)hh.h[1]);
            x2h[(size_t)row * 64 + lane] = hh.u;
            x2l[(size_t)row * 64 + lane] = ll.u;
        }
    }

    #pragma unroll
    for (int m = 32; m > 0; m >>= 1) {
        s22 += __shfl_xor(s22, m);
        s12 += __shfl_xor(s12, m);
    }
    if (lane == 0) {
        if (row < S) {
            float iv = rsqrtf(s22);
            invn[row] = iv;
            if (row < B) thr[row] = s12 * iv;
        }
        if (row < B) row_count[row] = 0;
    }
}

// ---------- Kernel B (fast): DMA-staged fp16x3 MFMA GEMM + compare-count ----------
// 128x128 tile, 4 waves of 64x64 (2x2 tiles of 32x32), BK=32, double-buffered.
// LDS planes FRAGMENT-ORDERED: block(rg 0..3, ks2 0..1) of 1KB; lane l holds
// row m = rg*32 + (l&31), halves k = ks2*16 + (l>>5)*8 .. +8 at block + l*16B.
// global_load_lds: per-lane global src picks exactly that element range;
// LDS dst = uniform block base + lane*16 (HW rule) -> layout matches by design.
// Wave w stages plane w (0:As_hi 1:As_lo 2:Bs_hi 3:Bs_lo).
__global__ __launch_bounds__(256) void count_kernel_fast(
    const _Float16* __restrict__ x1h, const _Float16* __restrict__ x1l,
    const _Float16* __restrict__ x2h, const _Float16* __restrict__ x2l,
    const float* __restrict__ invn, const float* __restrict__ thr,
    int* __restrict__ row_count)
{
    __shared__ __align__(16) _Float16 AB[2][4][4096]; // [buf][plane][halves] = 64KB
    __shared__ float s_thr[128], s_invn[128];
    __shared__ int cnt_s[128];

    const int tid  = threadIdx.x;
    const int wave = tid >> 6;
    const int lane = tid & 63;
    const int row0 = blockIdx.y * 128;
    const int col0 = blockIdx.x * 128;
    const int wr = (wave >> 1) * 64;   // wave row offset
    const int wc = (wave & 1) * 64;    // wave col offset

    if (tid < 128) {
        cnt_s[tid]  = 0;
        s_thr[tid]  = thr[row0 + tid];
        s_invn[tid] = invn[col0 + tid];
    }

    // staging source base for this wave's plane
    const _Float16* gplane = (wave == 0) ? x1h : (wave == 1) ? x1l
                           : (wave == 2) ? x2h : x2l;
    const int tbase = (wave < 2) ? row0 : col0;
    const _Float16* gbase =
        gplane + (size_t)(tbase + (lane & 31)) * KDIM + ((lane >> 5) * 8);

    floatx16 acc[2][2];
    #pragma unroll
    for (int a = 0; a < 2; a++)
        #pragma unroll
        for (int b = 0; b < 2; b++)
            #pragma unroll
            for (int i = 0; i < 16; i++) acc[a][b][i] = 0.f;

    const int wrg = wr >> 5;
    const int wcg = wc >> 5;
    const int lane8 = lane * 8;

    // prologue: chunk 0 -> buf 0
    #pragma unroll
    for (int rg = 0; rg < 4; rg++)
        #pragma unroll
        for (int k2 = 0; k2 < 2; k2++)
            gload16(gbase + rg * (32 * KDIM) + k2 * 16,
                    &AB[0][wave][(rg * 2 + k2) * 512]);
    __syncthreads();

    #pragma unroll
    for (int t = 0; t < 4; t++) {
        const int cur = t & 1;
        // early-issue next chunk's DMA into the other buffer; the barrier's
        // vmcnt(0) drain then lands AFTER this iteration's MFMAs.
        if (t < 3) {
            #pragma unroll
            for (int rg = 0; rg < 4; rg++)
                #pragma unroll
                for (int k2 = 0; k2 < 2; k2++)
                    gload16(gbase + rg * (32 * KDIM) + k2 * 16 + (t + 1) * 32,
                            &AB[cur ^ 1][wave][(rg * 2 + k2) * 512]);
        }

        #pragma unroll
        for (int ks2 = 0; ks2 < 2; ks2++) {
            half8 ah[2], al[2], bh[2], bl[2];
            #pragma unroll
            for (int u = 0; u < 2; u++) {
                const int oa = ((wrg + u) * 2 + ks2) * 512 + lane8;
                ah[u] = *(const half8*)&AB[cur][0][oa];
                al[u] = *(const half8*)&AB[cur][1][oa];
                const int ob = ((wcg + u) * 2 + ks2) * 512 + lane8;
                bh[u] = *(const half8*)&AB[cur][2][ob];
                bl[u] = *(const half8*)&AB[cur][3][ob];
            }
            #pragma unroll
            for (int mt = 0; mt < 2; mt++)
                #pragma unroll
                for (int nt = 0; nt < 2; nt++) {
                    acc[mt][nt] = __builtin_amdgcn_mfma_f32_32x32x16_f16(al[mt], bh[nt], acc[mt][nt], 0, 0, 0);
                    acc[mt][nt] = __builtin_amdgcn_mfma_f32_32x32x16_f16(ah[mt], bl[nt], acc[mt][nt], 0, 0, 0);
                    acc[mt][nt] = __builtin_amdgcn_mfma_f32_32x32x16_f16(ah[mt], bh[nt], acc[mt][nt], 0, 0, 0);
                }
        }
        __syncthreads();
    }

    // ---- epilogue: normalize, compare vs diag threshold, ballot-count ----
    // C/D layout (32x32): col = lane&31, row = (reg&3) + 8*(reg>>2) + 4*(lane>>5)
    const int cm = lane & 31;
    const int hw = lane >> 5;
    const float iv0 = s_invn[wc + cm];
    const float iv1 = s_invn[wc + 32 + cm];
    const int gc0 = col0 + wc + cm;
    const int gc1 = gc0 + 32;

    #pragma unroll
    for (int mt = 0; mt < 2; mt++) {
        #pragma unroll
        for (int reg = 0; reg < 16; reg++) {
            const int rbase = wr + mt * 32 + (reg & 3) + 8 * (reg >> 2);
            const int rloc  = rbase + 4 * hw;
            const int grow  = row0 + rloc;
            const float t   = s_thr[rloc];
            const bool p0 = (acc[mt][0][reg] * iv0 > t) && (gc0 != grow);
            const bool p1 = (acc[mt][1][reg] * iv1 > t) && (gc1 != grow);
            const unsigned long long b0 = __ballot(p0);
            const unsigned long long b1 = __ballot(p1);
            if (lane == 0) {
                const int clo = __popcll(b0 & 0xffffffffULL) + __popcll(b1 & 0xffffffffULL);
                if (clo) atomicAdd(&cnt_s[rbase], clo);
            } else if (lane == 32) {
                const int chi = __popcll(b0 >> 32) + __popcll(b1 >> 32);
                if (chi) atomicAdd(&cnt_s[rbase + 4], chi);
            }
        }
    }
    __syncthreads();
    if (tid < 128) {
        const int v = cnt_s[tid];
        if (v) atomicAdd(&row_count[row0 + tid], v);
    }
}

// ---------- Kernel B (fallback, proven): in-kernel conversion path ----------
__global__ __launch_bounds__(256) void count_kernel_conv(
    const float* __restrict__ x1, const float* __restrict__ x2,
    const float* __restrict__ invn, const float* __restrict__ thr,
    int* __restrict__ row_count)
{
    __shared__ __align__(16) _Float16 As_hi[4096], As_lo[4096];
    __shared__ __align__(16) _Float16 Bs_hi[4096], Bs_lo[4096];
    __shared__ float s_thr[128], s_invn[128];
    __shared__ int cnt_s[128];

    const int tid  = threadIdx.x;
    const int wave = tid >> 6;
    const int lane = tid & 63;
    const int row0 = blockIdx.y * 128;
    const int col0 = blockIdx.x * 128;
    const int wr = (wave >> 1) * 64;
    const int wc = (wave & 1) * 64;

    if (tid < 128) {
        cnt_s[tid]  = 0;
        s_thr[tid]  = thr[row0 + tid];
        s_invn[tid] = invn[col0 + tid];
    }

    floatx16 acc[2][2];
    #pragma unroll
    for (int a = 0; a < 2; a++)
        #pragma unroll
        for (int b = 0; b < 2; b++)
            #pragma unroll
            for (int i = 0; i < 16; i++) acc[a][b][i] = 0.f;

    const int sr   = tid >> 1;
    const int sks2 = tid & 1;
    const int wbase = ((sr >> 5) * 2 + sks2) * 512 + (sr & 31) * 8;
    const size_t ga = (size_t)(row0 + sr) * KDIM + sks2 * 16;
    const size_t gb = (size_t)(col0 + sr) * KDIM + sks2 * 16;

    const int wrg = wr >> 5;
    const int wcg = wc >> 5;
    const int lane8 = lane * 8;

    for (int kc = 0; kc < KDIM; kc += 32) {
        __syncthreads();
        {
            const float* p = &x1[ga + kc];
            float v[16];
            *(float4*)&v[0]  = *(const float4*)(p);
            *(float4*)&v[4]  = *(const float4*)(p + 4);
            *(float4*)&v[8]  = *(const float4*)(p + 8);
            *(float4*)&v[12] = *(const float4*)(p + 12);
            half8 h0, h1, l0, l1;
            #pragma unroll
            for (int i = 0; i < 8; i++) {
                _Float16 h = (_Float16)v[i];
                h0[i] = h; l0[i] = (_Float16)(v[i] - (float)h);
                _Float16 g = (_Float16)v[i + 8];
                h1[i] = g; l1[i] = (_Float16)(v[i + 8] - (float)g);
            }
            *(half8*)&As_hi[wbase]       = h0;
            *(half8*)&As_hi[wbase + 256] = h1;
            *(half8*)&As_lo[wbase]       = l0;
            *(half8*)&As_lo[wbase + 256] = l1;
        }
        {
            const float* p = &x2[gb + kc];
            float v[16];
            *(float4*)&v[0]  = *(const float4*)(p);
            *(float4*)&v[4]  = *(const float4*)(p + 4);
            *(float4*)&v[8]  = *(const float4*)(p + 8);
            *(float4*)&v[12] = *(const float4*)(p + 12);
            half8 h0, h1, l0, l1;
            #pragma unroll
            for (int i = 0; i < 8; i++) {
                _Float16 h = (_Float16)v[i];
                h0[i] = h; l0[i] = (_Float16)(v[i] - (float)h);
                _Float16 g = (_Float16)v[i + 8];
                h1[i] = g; l1[i] = (_Float16)(v[i + 8] - (float)g);
            }
            *(half8*)&Bs_hi[wbase]       = h0;
            *(half8*)&Bs_hi[wbase + 256] = h1;
            *(half8*)&Bs_lo[wbase]       = l0;
            *(half8*)&Bs_lo[wbase + 256] = l1;
        }
        __syncthreads();

        #pragma unroll
        for (int ks2 = 0; ks2 < 2; ks2++) {
            half8 ah[2], al[2], bh[2], bl[2];
            #pragma unroll
            for (int t = 0; t < 2; t++) {
                const int oa = ((wrg + t) * 2 + ks2) * 512 + lane8;
                ah[t] = *(const half8*)&As_hi[oa];
                al[t] = *(const half8*)&As_lo[oa];
                const int ob = ((wcg + t) * 2 + ks2) * 512 + lane8;
                bh[t] = *(const half8*)&Bs_hi[ob];
                bl[t] = *(const half8*)&Bs_lo[ob];
            }
            #pragma unroll
            for (int mt = 0; mt < 2; mt++)
                #pragma unroll
                for (int nt = 0; nt < 2; nt++) {
                    acc[mt][nt] = __builtin_amdgcn_mfma_f32_32x32x16_f16(al[mt], bh[nt], acc[mt][nt], 0, 0, 0);
                    acc[mt][nt] = __builtin_amdgcn_mfma_f32_32x32x16_f16(ah[mt], bl[nt], acc[mt][nt], 0, 0, 0);
                    acc[mt][nt] = __builtin_amdgcn_mfma_f32_32x32x16_f16(ah[mt], bh[nt], acc[mt][nt], 0, 0, 0);
                }
        }
    }

    const int cm = lane & 31;
    const int hw = lane >> 5;
    const float iv0 = s_invn[wc + cm];
    const float iv1 = s_invn[wc + 32 + cm];
    const int gc0 = col0 + wc + cm;
    const int gc1 = gc0 + 32;

    #pragma unroll
    for (int mt = 0; mt < 2; mt++) {
        #pragma unroll
        for (int reg = 0; reg < 16; reg++) {
            const int rbase = wr + mt * 32 + (reg & 3) + 8 * (reg >> 2);
            const int rloc  = rbase + 4 * hw;
            const int grow  = row0 + rloc;
            const float t   = s_thr[rloc];
            const bool p0 = (acc[mt][0][reg] * iv0 > t) && (gc0 != grow);
            const bool p1 = (acc[mt][1][reg] * iv1 > t) && (gc1 != grow);
            const unsigned long long b0 = __ballot(p0);
            const unsigned long long b1 = __ballot(p1);
            if (lane == 0) {
                const int clo = __popcll(b0 & 0xffffffffULL) + __popcll(b1 & 0xffffffffULL);
                if (clo) atomicAdd(&cnt_s[rbase], clo);
            } else if (lane == 32) {
                const int chi = __popcll(b0 >> 32) + __popcll(b1 >> 32);
                if (chi) atomicAdd(&cnt_s[rbase + 4], chi);
            }
        }
    }
    __syncthreads();
    if (tid < 128) {
        const int v = cnt_s[tid];
        if (v) atomicAdd(&row_count[row0 + tid], v);
    }
}

// ---------- Kernel C: final reduction ----------
__global__ __launch_bounds__(1024) void finalize_kernel(
    const int* __restrict__ row_count, float* __restrict__ out, int B, int nper)
{
    __shared__ int wsum[16];
    const int t = threadIdx.x;
    int c = 0;
    for (int i = t; i < B; i += 1024) c += (row_count[i] < nper) ? 1 : 0;
    #pragma unroll
    for (int m = 32; m > 0; m >>= 1) c += __shfl_xor(c, m);
    if ((t & 63) == 0) wsum[t >> 6] = c;
    __syncthreads();
    if (t == 0) {
        int tot = 0;
        #pragma unroll
        for (int w = 0; w < 16; w++) tot += wsum[w];
        out[0] = (float)tot / (float)B;
    }
}

extern "C" void kernel_launch(void* const* d_in, const int* in_sizes, int n_in,
                              void* d_out, int out_size, void* d_ws, size_t ws_size,
                              hipStream_t stream)
{
    const float* x1 = (const float*)d_in[0];
    const float* x2 = (const float*)d_in[1];
    const int B = in_sizes[0] / KDIM;     // 8192
    const int S = in_sizes[1] / KDIM;     // 8192
    const int nper = S / 100 + 1;         // 82

    float* invn      = (float*)d_ws;
    float* thr       = invn + S;
    int*   row_count = (int*)(thr + B);

    uintptr_t ap = ((uintptr_t)(row_count + B) + 15) & ~(uintptr_t)15;
    _Float16* x1h = (_Float16*)ap;
    _Float16* x1l = x1h + (size_t)B * KDIM;
    _Float16* x2h = x1l + (size_t)B * KDIM;
    _Float16* x2l = x2h + (size_t)S * KDIM;
    const size_t need = (size_t)((char*)(x2l + (size_t)S * KDIM) - (char*)d_ws);
    const int fast = (ws_size >= need) ? 1 : 0;

    const int mx = (B > S) ? B : S;
    prep_kernel<<<(mx + 3) / 4, 256, 0, stream>>>(
        x1, x2, invn, thr, row_count,
        (unsigned*)x1h, (unsigned*)x1l, (unsigned*)x2h, (unsigned*)x2l,
        B, S, fast);

    dim3 grid(S / 128, B / 128);
    if (fast)
        count_kernel_fast<<<grid, 256, 0, stream>>>(x1h, x1l, x2h, x2l, invn, thr, row_count);
    else
        count_kernel_conv<<<grid, 256, 0, stream>>>(x1, x2, invn, thr, row_count);

    finalize_kernel<<<1, 1024, 0, stream>>>(row_count, (float*)d_out, B, nper);
}

// Round 2
// 135.534 us; speedup vs baseline: 1.3097x; 1.3097x over previous
//
#include <hip/hip_runtime.h>

// out = mean_i( rank_of_diag(cos_sim(x1,x2))_i < nper ), nper = S/100+1.
// rank_i = #{ j != i : dot(x1_i,x2_j)*inv||x2_j|| > dot(x1_i,x2_i)*inv||x2_i|| }
// GEMM via fp16x3 (Markidis split) MFMA: x=hi+lo; hi*hi + hi*lo + lo*hi.
// Dropped lo*lo ~2^-22 rel/term -> dot err ~3e-6 << 4.5e-3 order-stat spacing.
//
// R2: hi/lo planes precomputed once in prep (kills 64x redundant cvt VALU);
// count kernel keeps the PROVEN 34KB single-buffer LDS layout (4 blocks/CU --
// the R1 DMA/double-buffer variant dropped to 2 blocks/CU and regressed), but
// stages from the fp16 planes with reg-staged half8 loads issued EARLY (next
// chunk's loads before current chunk's MFMAs) so vmcnt waits land after ~400
// cycles of compute instead of 0.

#define KDIM 128

typedef _Float16 half8 __attribute__((ext_vector_type(8)));
typedef float floatx16 __attribute__((ext_vector_type(16)));

// ---------- Kernel A: 1/||x2||, diag threshold, zero counters, fp16 hi/lo planes ----------
__global__ __launch_bounds__(256) void prep_kernel(
    const float* __restrict__ x1, const float* __restrict__ x2,
    float* __restrict__ invn, float* __restrict__ thr,
    int* __restrict__ row_count,
    unsigned* __restrict__ x1h, unsigned* __restrict__ x1l,
    unsigned* __restrict__ x2h, unsigned* __restrict__ x2l,
    int B, int S, int wplanes)
{
    const int wave = threadIdx.x >> 6;
    const int lane = threadIdx.x & 63;
    const int row = blockIdx.x * 4 + wave;
    if (row >= S && row >= B) return;

    float s22 = 0.f, s12 = 0.f;
    float2 a = make_float2(0.f, 0.f), b = make_float2(0.f, 0.f);
    if (row < B) a = ((const float2*)&x1[(size_t)row * KDIM])[lane];
    if (row < S) {
        b = ((const float2*)&x2[(size_t)row * KDIM])[lane];
        s22 = fmaf(b.x, b.x, b.y * b.y);
        s12 = fmaf(a.x, b.x, a.y * b.y);
    }

    if (wplanes) {
        if (row < B) {
            union { _Float16 h[2]; unsigned u; } hh, ll;
            hh.h[0] = (_Float16)a.x; ll.h[0] = (_Float16)(a.x - (float)hh.h[0]);
            hh.h[1] = (_Float16)a.y; ll.h[1] = (_Float16)(a.y - (float)hh.h[1]);
            x1h[(size_t)row * 64 + lane] = hh.u;
            x1l[(size_t)row * 64 + lane] = ll.u;
        }
        if (row < S) {
            union { _Float16 h[2]; unsigned u; } hh, ll;
            hh.h[0] = (_Float16)b.x; ll.h[0] = (_Float16)(b.x - (float)hh.h[0]);
            hh.h[1] = (_Float16)b.y; ll.h[1] = (_Float16)(b.y - (float)hh.h[1]);
            x2h[(size_t)row * 64 + lane] = hh.u;
            x2l[(size_t)row * 64 + lane] = ll.u;
        }
    }

    #pragma unroll
    for (int m = 32; m > 0; m >>= 1) {
        s22 += __shfl_xor(s22, m);
        s12 += __shfl_xor(s12, m);
    }
    if (lane == 0) {
        if (row < S) {
            float iv = rsqrtf(s22);
            invn[row] = iv;
            if (row < B) thr[row] = s12 * iv;
        }
        if (row < B) row_count[row] = 0;
    }
}

// ---------- Kernel B (fast): plane-staged fp16x3 MFMA GEMM + compare-count ----------
// 128x128 tile, 4 waves of 64x64 (2x2 tiles of 32x32), BK=32, single LDS buffer
// (34KB -> 4 blocks/CU). LDS planes FRAGMENT-ORDERED: block(rg 0..3, ks2 0..1)
// of 1KB; lane l holds row m=rg*32+(l&31), k=(l>>5)*8+j at block + l*16B.
// Reads: lane-contiguous ds_read_b128 (0 conflicts). Writes: 2-way (free).
// Staging: 8x half8 (16B) fully-coalesced global loads per thread per chunk,
// issued one chunk EARLY so latency hides under the current chunk's MFMAs.
__global__ __launch_bounds__(256) void count_kernel_fast(
    const _Float16* __restrict__ x1h, const _Float16* __restrict__ x1l,
    const _Float16* __restrict__ x2h, const _Float16* __restrict__ x2l,
    const float* __restrict__ invn, const float* __restrict__ thr,
    int* __restrict__ row_count)
{
    __shared__ __align__(16) _Float16 Ah[4096], Al[4096];
    __shared__ __align__(16) _Float16 Bh[4096], Bl[4096];
    __shared__ float s_thr[128], s_invn[128];
    __shared__ int cnt_s[128];

    const int tid  = threadIdx.x;
    const int wave = tid >> 6;
    const int lane = tid & 63;
    const int row0 = blockIdx.y * 128;
    const int col0 = blockIdx.x * 128;
    const int wr = (wave >> 1) * 64;   // wave row offset
    const int wc = (wave & 1) * 64;    // wave col offset

    if (tid < 128) {
        cnt_s[tid]  = 0;
        s_thr[tid]  = thr[row0 + tid];
        s_invn[tid] = invn[col0 + tid];
    }

    // staging coords: thread covers (row sr, k-16-group sks2): 16 halves/plane
    const int sr   = tid >> 1;       // 0..127
    const int sks2 = tid & 1;        // 0/1
    const int wbase = ((sr >> 5) * 2 + sks2) * 512 + (sr & 31) * 8;
    const size_t ga = (size_t)(row0 + sr) * KDIM + sks2 * 16;
    const size_t gb = (size_t)(col0 + sr) * KDIM + sks2 * 16;
    const _Float16* pah = x1h + ga;
    const _Float16* pal = x1l + ga;
    const _Float16* pbh = x2h + gb;
    const _Float16* pbl = x2l + gb;

    floatx16 acc[2][2];
    #pragma unroll
    for (int a = 0; a < 2; a++)
        #pragma unroll
        for (int b = 0; b < 2; b++)
            #pragma unroll
            for (int i = 0; i < 16; i++) acc[a][b][i] = 0.f;

    const int wrg = wr >> 5;         // A rowgroup base: 0 or 2
    const int wcg = wc >> 5;         // B rowgroup base: 0 or 2
    const int lane8 = lane * 8;

    // prologue: chunk 0 into regs
    half8 r[2][8];
    r[0][0] = *(const half8*)(pah);     r[0][1] = *(const half8*)(pah + 8);
    r[0][2] = *(const half8*)(pal);     r[0][3] = *(const half8*)(pal + 8);
    r[0][4] = *(const half8*)(pbh);     r[0][5] = *(const half8*)(pbh + 8);
    r[0][6] = *(const half8*)(pbl);     r[0][7] = *(const half8*)(pbl + 8);

    #pragma unroll
    for (int t = 0; t < 4; t++) {
        const int ph = t & 1;            // compile-time after unroll
        __syncthreads();                 // previous chunk fully consumed
        *(half8*)&Ah[wbase]       = r[ph][0];
        *(half8*)&Ah[wbase + 256] = r[ph][1];
        *(half8*)&Al[wbase]       = r[ph][2];
        *(half8*)&Al[wbase + 256] = r[ph][3];
        *(half8*)&Bh[wbase]       = r[ph][4];
        *(half8*)&Bh[wbase + 256] = r[ph][5];
        *(half8*)&Bl[wbase]       = r[ph][6];
        *(half8*)&Bl[wbase + 256] = r[ph][7];
        if (t < 3) {
            // early-issue next chunk's loads; their waitcnt lands at the
            // ds_writes AFTER the next barrier (~400 cyc of MFMA away)
            const int ko = (t + 1) * 32;
            r[ph ^ 1][0] = *(const half8*)(pah + ko);
            r[ph ^ 1][1] = *(const half8*)(pah + ko + 8);
            r[ph ^ 1][2] = *(const half8*)(pal + ko);
            r[ph ^ 1][3] = *(const half8*)(pal + ko + 8);
            r[ph ^ 1][4] = *(const half8*)(pbh + ko);
            r[ph ^ 1][5] = *(const half8*)(pbh + ko + 8);
            r[ph ^ 1][6] = *(const half8*)(pbl + ko);
            r[ph ^ 1][7] = *(const half8*)(pbl + ko + 8);
        }
        __syncthreads();

        // ---- MFMA over the two K=16 steps of this chunk ----
        #pragma unroll
        for (int ks2 = 0; ks2 < 2; ks2++) {
            half8 ah[2], al[2], bh[2], bl[2];
            #pragma unroll
            for (int u = 0; u < 2; u++) {
                const int oa = ((wrg + u) * 2 + ks2) * 512 + lane8;
                ah[u] = *(const half8*)&Ah[oa];
                al[u] = *(const half8*)&Al[oa];
                const int ob = ((wcg + u) * 2 + ks2) * 512 + lane8;
                bh[u] = *(const half8*)&Bh[ob];
                bl[u] = *(const half8*)&Bl[ob];
            }
            #pragma unroll
            for (int mt = 0; mt < 2; mt++)
                #pragma unroll
                for (int nt = 0; nt < 2; nt++) {
                    acc[mt][nt] = __builtin_amdgcn_mfma_f32_32x32x16_f16(al[mt], bh[nt], acc[mt][nt], 0, 0, 0);
                    acc[mt][nt] = __builtin_amdgcn_mfma_f32_32x32x16_f16(ah[mt], bl[nt], acc[mt][nt], 0, 0, 0);
                    acc[mt][nt] = __builtin_amdgcn_mfma_f32_32x32x16_f16(ah[mt], bh[nt], acc[mt][nt], 0, 0, 0);
                }
        }
    }

    // ---- epilogue: normalize, compare vs diag threshold, ballot-count ----
    // C/D layout (32x32): col = lane&31, row = (reg&3) + 8*(reg>>2) + 4*(lane>>5)
    const int cm = lane & 31;
    const int hw = lane >> 5;
    const float iv0 = s_invn[wc + cm];
    const float iv1 = s_invn[wc + 32 + cm];
    const int gc0 = col0 + wc + cm;
    const int gc1 = gc0 + 32;

    #pragma unroll
    for (int mt = 0; mt < 2; mt++) {
        #pragma unroll
        for (int reg = 0; reg < 16; reg++) {
            const int rbase = wr + mt * 32 + (reg & 3) + 8 * (reg >> 2);
            const int rloc  = rbase + 4 * hw;
            const int grow  = row0 + rloc;
            const float t   = s_thr[rloc];
            const bool p0 = (acc[mt][0][reg] * iv0 > t) && (gc0 != grow);
            const bool p1 = (acc[mt][1][reg] * iv1 > t) && (gc1 != grow);
            const unsigned long long b0 = __ballot(p0);
            const unsigned long long b1 = __ballot(p1);
            if (lane == 0) {
                const int clo = __popcll(b0 & 0xffffffffULL) + __popcll(b1 & 0xffffffffULL);
                if (clo) atomicAdd(&cnt_s[rbase], clo);
            } else if (lane == 32) {
                const int chi = __popcll(b0 >> 32) + __popcll(b1 >> 32);
                if (chi) atomicAdd(&cnt_s[rbase + 4], chi);
            }
        }
    }
    __syncthreads();
    if (tid < 128) {
        const int v = cnt_s[tid];
        if (v) atomicAdd(&row_count[row0 + tid], v);
    }
}

// ---------- Kernel B (fallback, proven): in-kernel conversion path ----------
__global__ __launch_bounds__(256) void count_kernel_conv(
    const float* __restrict__ x1, const float* __restrict__ x2,
    const float* __restrict__ invn, const float* __restrict__ thr,
    int* __restrict__ row_count)
{
    __shared__ __align__(16) _Float16 As_hi[4096], As_lo[4096];
    __shared__ __align__(16) _Float16 Bs_hi[4096], Bs_lo[4096];
    __shared__ float s_thr[128], s_invn[128];
    __shared__ int cnt_s[128];

    const int tid  = threadIdx.x;
    const int wave = tid >> 6;
    const int lane = tid & 63;
    const int row0 = blockIdx.y * 128;
    const int col0 = blockIdx.x * 128;
    const int wr = (wave >> 1) * 64;
    const int wc = (wave & 1) * 64;

    if (tid < 128) {
        cnt_s[tid]  = 0;
        s_thr[tid]  = thr[row0 + tid];
        s_invn[tid] = invn[col0 + tid];
    }

    floatx16 acc[2][2];
    #pragma unroll
    for (int a = 0; a < 2; a++)
        #pragma unroll
        for (int b = 0; b < 2; b++)
            #pragma unroll
            for (int i = 0; i < 16; i++) acc[a][b][i] = 0.f;

    const int sr   = tid >> 1;
    const int sks2 = tid & 1;
    const int wbase = ((sr >> 5) * 2 + sks2) * 512 + (sr & 31) * 8;
    const size_t ga = (size_t)(row0 + sr) * KDIM + sks2 * 16;
    const size_t gb = (size_t)(col0 + sr) * KDIM + sks2 * 16;

    const int wrg = wr >> 5;
    const int wcg = wc >> 5;
    const int lane8 = lane * 8;

    for (int kc = 0; kc < KDIM; kc += 32) {
        __syncthreads();
        {
            const float* p = &x1[ga + kc];
            float v[16];
            *(float4*)&v[0]  = *(const float4*)(p);
            *(float4*)&v[4]  = *(const float4*)(p + 4);
            *(float4*)&v[8]  = *(const float4*)(p + 8);
            *(float4*)&v[12] = *(const float4*)(p + 12);
            half8 h0, h1, l0, l1;
            #pragma unroll
            for (int i = 0; i < 8; i++) {
                _Float16 h = (_Float16)v[i];
                h0[i] = h; l0[i] = (_Float16)(v[i] - (float)h);
                _Float16 g = (_Float16)v[i + 8];
                h1[i] = g; l1[i] = (_Float16)(v[i + 8] - (float)g);
            }
            *(half8*)&As_hi[wbase]       = h0;
            *(half8*)&As_hi[wbase + 256] = h1;
            *(half8*)&As_lo[wbase]       = l0;
            *(half8*)&As_lo[wbase + 256] = l1;
        }
        {
            const float* p = &x2[gb + kc];
            float v[16];
            *(float4*)&v[0]  = *(const float4*)(p);
            *(float4*)&v[4]  = *(const float4*)(p + 4);
            *(float4*)&v[8]  = *(const float4*)(p + 8);
            *(float4*)&v[12] = *(const float4*)(p + 12);
            half8 h0, h1, l0, l1;
            #pragma unroll
            for (int i = 0; i < 8; i++) {
                _Float16 h = (_Float16)v[i];
                h0[i] = h; l0[i] = (_Float16)(v[i] - (float)h);
                _Float16 g = (_Float16)v[i + 8];
                h1[i] = g; l1[i] = (_Float16)(v[i + 8] - (float)g);
            }
            *(half8*)&Bs_hi[wbase]       = h0;
            *(half8*)&Bs_hi[wbase + 256] = h1;
            *(half8*)&Bs_lo[wbase]       = l0;
            *(half8*)&Bs_lo[wbase + 256] = l1;
        }
        __syncthreads();

        #pragma unroll
        for (int ks2 = 0; ks2 < 2; ks2++) {
            half8 ah[2], al[2], bh[2], bl[2];
            #pragma unroll
            for (int t = 0; t < 2; t++) {
                const int oa = ((wrg + t) * 2 + ks2) * 512 + lane8;
                ah[t] = *(const half8*)&As_hi[oa];
                al[t] = *(const half8*)&As_lo[oa];
                const int ob = ((wcg + t) * 2 + ks2) * 512 + lane8;
                bh[t] = *(const half8*)&Bs_hi[ob];
                bl[t] = *(const half8*)&Bs_lo[ob];
            }
            #pragma unroll
            for (int mt = 0; mt < 2; mt++)
                #pragma unroll
                for (int nt = 0; nt < 2; nt++) {
                    acc[mt][nt] = __builtin_amdgcn_mfma_f32_32x32x16_f16(al[mt], bh[nt], acc[mt][nt], 0, 0, 0);
                    acc[mt][nt] = __builtin_amdgcn_mfma_f32_32x32x16_f16(ah[mt], bl[nt], acc[mt][nt], 0, 0, 0);
                    acc[mt][nt] = __builtin_amdgcn_mfma_f32_32x32x16_f16(ah[mt], bh[nt], acc[mt][nt], 0, 0, 0);
                }
        }
    }

    const int cm = lane & 31;
    const int hw = lane >> 5;
    const float iv0 = s_invn[wc + cm];
    const float iv1 = s_invn[wc + 32 + cm];
    const int gc0 = col0 + wc + cm;
    const int gc1 = gc0 + 32;

    #pragma unroll
    for (int mt = 0; mt < 2; mt++) {
        #pragma unroll
        for (int reg = 0; reg < 16; reg++) {
            const int rbase = wr + mt * 32 + (reg & 3) + 8 * (reg >> 2);
            const int rloc  = rbase + 4 * hw;
            const int grow  = row0 + rloc;
            const float t   = s_thr[rloc];
            const bool p0 = (acc[mt][0][reg] * iv0 > t) && (gc0 != grow);
            const bool p1 = (acc[mt][1][reg] * iv1 > t) && (gc1 != grow);
            const unsigned long long b0 = __ballot(p0);
            const unsigned long long b1 = __ballot(p1);
            if (lane == 0) {
                const int clo = __popcll(b0 & 0xffffffffULL) + __popcll(b1 & 0xffffffffULL);
                if (clo) atomicAdd(&cnt_s[rbase], clo);
            } else if (lane == 32) {
                const int chi = __popcll(b0 >> 32) + __popcll(b1 >> 32);
                if (chi) atomicAdd(&cnt_s[rbase + 4], chi);
            }
        }
    }
    __syncthreads();
    if (tid < 128) {
        const int v = cnt_s[tid];
        if (v) atomicAdd(&row_count[row0 + tid], v);
    }
}

// ---------- Kernel C: final reduction ----------
__global__ __launch_bounds__(1024) void finalize_kernel(
    const int* __restrict__ row_count, float* __restrict__ out, int B, int nper)
{
    __shared__ int wsum[16];
    const int t = threadIdx.x;
    int c = 0;
    for (int i = t; i < B; i += 1024) c += (row_count[i] < nper) ? 1 : 0;
    #pragma unroll
    for (int m = 32; m > 0; m >>= 1) c += __shfl_xor(c, m);
    if ((t & 63) == 0) wsum[t >> 6] = c;
    __syncthreads();
    if (t == 0) {
        int tot = 0;
        #pragma unroll
        for (int w = 0; w < 16; w++) tot += wsum[w];
        out[0] = (float)tot / (float)B;
    }
}

extern "C" void kernel_launch(void* const* d_in, const int* in_sizes, int n_in,
                              void* d_out, int out_size, void* d_ws, size_t ws_size,
                              hipStream_t stream)
{
    const float* x1 = (const float*)d_in[0];
    const float* x2 = (const float*)d_in[1];
    const int B = in_sizes[0] / KDIM;     // 8192
    const int S = in_sizes[1] / KDIM;     // 8192
    const int nper = S / 100 + 1;         // 82

    float* invn      = (float*)d_ws;
    float* thr       = invn + S;
    int*   row_count = (int*)(thr + B);

    uintptr_t ap = ((uintptr_t)(row_count + B) + 15) & ~(uintptr_t)15;
    _Float16* x1h = (_Float16*)ap;
    _Float16* x1l = x1h + (size_t)B * KDIM;
    _Float16* x2h = x1l + (size_t)B * KDIM;
    _Float16* x2l = x2h + (size_t)S * KDIM;
    const size_t need = (size_t)((char*)(x2l + (size_t)S * KDIM) - (char*)d_ws);
    const int fast = (ws_size >= need) ? 1 : 0;

    const int mx = (B > S) ? B : S;
    prep_kernel<<<(mx + 3) / 4, 256, 0, stream>>>(
        x1, x2, invn, thr, row_count,
        (unsigned*)x1h, (unsigned*)x1l, (unsigned*)x2h, (unsigned*)x2l,
        B, S, fast);

    dim3 grid(S / 128, B / 128);
    if (fast)
        count_kernel_fast<<<grid, 256, 0, stream>>>(x1h, x1l, x2h, x2l, invn, thr, row_count);
    else
        count_kernel_conv<<<grid, 256, 0, stream>>>(x1, x2, invn, thr, row_count);

    finalize_kernel<<<1, 1024, 0, stream>>>(row_count, (float*)d_out, B, nper);
}